// Round 4
// baseline (270.277 us; speedup 1.0000x reference)
//
#include <hip/hip_runtime.h>
#include <math.h>

constexpr int kNodes = 50000;
constexpr int kDim   = 128;
constexpr int kEdges = 600000;
constexpr float kAlpha = 0.2f;

constexpr int kScanChunk  = 1024;
constexpr int kScanBlocks = (kNodes + kScanChunk - 1) / kScanChunk; // 49

// ws layout (4-byte units):
// [0]=gmax [1]=gsum [2..4) pad
constexpr int kOffCounts   = 4;
constexpr int kOffOffsets  = kOffCounts + kNodes;
constexpr int kOffCursor   = kOffOffsets + kNodes;
constexpr int kOffCsrSD    = kOffCursor + kNodes;        // int2 per CSR slot (src,dst); offset 150004 (even)
constexpr int kOffMeta     = kOffCsrSD + 2 * kEdges;     // float2 per CSR slot (dst,score); even
constexpr int kOffBlockSum = kOffMeta + 2 * kEdges;

__device__ __forceinline__ void atomicMaxF(float* addr, float val) {
    if (val >= 0.0f) atomicMax((int*)addr, __float_as_int(val));
    else             atomicMin((unsigned int*)addr, __float_as_uint(val));
}

__global__ void init_kernel(float* wsf, int* counts) {
    int i = blockIdx.x * blockDim.x + threadIdx.x;
    if (i == 0) { wsf[0] = -INFINITY; wsf[1] = 0.0f; }
    for (; i < kNodes; i += gridDim.x * blockDim.x) counts[i] = 0;
}

__global__ void hist_kernel(const int2* __restrict__ rel2, int* __restrict__ counts) {
    for (int e = blockIdx.x * blockDim.x + threadIdx.x; e < kEdges; e += gridDim.x * blockDim.x)
        atomicAdd(&counts[rel2[e].x], 1);
}

__global__ void scanA_kernel(const int* __restrict__ counts, int* __restrict__ blocksum) {
    const int base = blockIdx.x * kScanChunk;
    int acc = 0;
    #pragma unroll
    for (int j = 0; j < 4; ++j) {
        const int i = base + 4 * (int)threadIdx.x + j;
        if (i < kNodes) acc += counts[i];
    }
    __shared__ int red[256];
    red[threadIdx.x] = acc;
    __syncthreads();
    for (int s = blockDim.x >> 1; s > 0; s >>= 1) {
        if ((int)threadIdx.x < s) red[threadIdx.x] += red[threadIdx.x + s];
        __syncthreads();
    }
    if (threadIdx.x == 0) blocksum[blockIdx.x] = red[0];
}

__global__ void scanB_kernel(int* __restrict__ blocksum) {
    __shared__ int lds[kScanBlocks];
    if ((int)threadIdx.x < kScanBlocks) lds[threadIdx.x] = blocksum[threadIdx.x];
    __syncthreads();
    if (threadIdx.x == 0) {
        int run = 0;
        for (int i = 0; i < kScanBlocks; ++i) { int t = lds[i]; lds[i] = run; run += t; }
    }
    __syncthreads();
    if ((int)threadIdx.x < kScanBlocks) blocksum[threadIdx.x] = lds[threadIdx.x];
}

__global__ void scanC_kernel(const int* __restrict__ counts,
                             const int* __restrict__ blocksum,
                             int* __restrict__ offsets,
                             int* __restrict__ cursor) {
    const int base = blockIdx.x * kScanChunk;
    const int lane = threadIdx.x & 63;
    const int wave = threadIdx.x >> 6;
    int c[4];
    int sum4 = 0;
    #pragma unroll
    for (int j = 0; j < 4; ++j) {
        const int i = base + 4 * (int)threadIdx.x + j;
        c[j] = (i < kNodes) ? counts[i] : 0;
        sum4 += c[j];
    }
    int incl = sum4;
    #pragma unroll
    for (int off = 1; off < 64; off <<= 1) {
        int v = __shfl_up(incl, off);
        if (lane >= off) incl += v;
    }
    __shared__ int waveSum[4];
    __shared__ int waveOff[4];
    if (lane == 63) waveSum[wave] = incl;
    __syncthreads();
    if (threadIdx.x == 0) {
        int run = 0;
        for (int w = 0; w < 4; ++w) { int t = waveSum[w]; waveOff[w] = run; run += t; }
    }
    __syncthreads();
    int excl = blocksum[blockIdx.x] + waveOff[wave] + (incl - sum4);
    #pragma unroll
    for (int j = 0; j < 4; ++j) {
        const int i = base + 4 * (int)threadIdx.x + j;
        if (i < kNodes) { offsets[i] = excl; cursor[i] = excl; }
        excl += c[j];
    }
}

// Scatter (src,dst) into CSR order.
__global__ void fillsd_kernel(const int2* __restrict__ rel2,
                              int* __restrict__ cursor,
                              int2* __restrict__ csrSD) {
    for (int e = blockIdx.x * blockDim.x + threadIdx.x; e < kEdges; e += gridDim.x * blockDim.x) {
        const int2 sd = rel2[e];
        const int pos = atomicAdd(&cursor[sd.x], 1);
        csrSD[pos] = sd;
    }
}

// Edge-parallel over CSR slots (src-sorted): consecutive slots share src rows
// -> L1 hits on the src gather. 16 lanes per slot, unroll x2 via stride.
__global__ void scores_csr_kernel(const float4* __restrict__ emb4,
                                  const int2* __restrict__ csrSD,
                                  float2* __restrict__ meta,
                                  float* __restrict__ gmax) {
    const int g    = threadIdx.x & 15;
    const int swid = (blockIdx.x * blockDim.x + threadIdx.x) >> 4;
    const int nsw  = (gridDim.x * blockDim.x) >> 4;

    float lmax = -INFINITY;
    for (int k0 = swid; k0 < kEdges; k0 += 2 * nsw) {
        const int k1 = k0 + nsw;
        const bool has1 = (k1 < kEdges);
        const int2 sd0 = csrSD[k0];
        const int2 sd1 = has1 ? csrSD[k1] : sd0;

        const long long sa0 = (long long)sd0.x * 32, da0 = (long long)sd0.y * 32;
        const long long sa1 = (long long)sd1.x * 32, da1 = (long long)sd1.y * 32;
        const float4 a00 = emb4[sa0 + g];
        const float4 b00 = emb4[da0 + g];
        const float4 a01 = emb4[sa0 + 16 + g];
        const float4 b01 = emb4[da0 + 16 + g];
        const float4 a10 = emb4[sa1 + g];
        const float4 b10 = emb4[da1 + g];
        const float4 a11 = emb4[sa1 + 16 + g];
        const float4 b11 = emb4[da1 + 16 + g];

        float p0 = a00.x*b00.x + a00.y*b00.y + a00.z*b00.z + a00.w*b00.w
                 + a01.x*b01.x + a01.y*b01.y + a01.z*b01.z + a01.w*b01.w;
        float p1 = a10.x*b10.x + a10.y*b10.y + a10.z*b10.z + a10.w*b10.w
                 + a11.x*b11.x + a11.y*b11.y + a11.z*b11.z + a11.w*b11.w;
        p0 += __shfl_xor(p0, 8);  p1 += __shfl_xor(p1, 8);
        p0 += __shfl_xor(p0, 4);  p1 += __shfl_xor(p1, 4);
        p0 += __shfl_xor(p0, 2);  p1 += __shfl_xor(p1, 2);
        p0 += __shfl_xor(p0, 1);  p1 += __shfl_xor(p1, 1);

        const float sc0 = p0 > 0.f ? p0 : kAlpha * p0;
        const float sc1 = p1 > 0.f ? p1 : kAlpha * p1;
        lmax = fmaxf(lmax, sc0);
        if (has1) lmax = fmaxf(lmax, sc1);
        if (g == 0) {
            meta[k0] = make_float2(__int_as_float(sd0.y), sc0);
            if (has1) meta[k1] = make_float2(__int_as_float(sd1.y), sc1);
        }
    }
    __shared__ float red[256];
    red[threadIdx.x] = lmax;
    __syncthreads();
    for (int s = blockDim.x >> 1; s > 0; s >>= 1) {
        if ((int)threadIdx.x < s) red[threadIdx.x] = fmaxf(red[threadIdx.x], red[threadIdx.x + s]);
        __syncthreads();
    }
    if (threadIdx.x == 0) atomicMaxF(gmax, red[0]);
}

__global__ void sumexp_kernel(const float2* __restrict__ meta,
                              const float* __restrict__ gmax,
                              float* __restrict__ gsum) {
    const float m = *gmax;
    float acc = 0.0f;
    for (int i = blockIdx.x * blockDim.x + threadIdx.x; i < kEdges; i += gridDim.x * blockDim.x)
        acc += expf(meta[i].y - m);
    __shared__ float red[256];
    red[threadIdx.x] = acc;
    __syncthreads();
    for (int s = blockDim.x >> 1; s > 0; s >>= 1) {
        if ((int)threadIdx.x < s) red[threadIdx.x] += red[threadIdx.x + s];
        __syncthreads();
    }
    if (threadIdx.x == 0) atomicAdd(gsum, red[0]);
}

// 32 lanes per node; exp computed inline (VALU is idle); unroll x2.
__global__ void gather_kernel(const float4* __restrict__ emb4,
                              const int* __restrict__ offsets,
                              const int* __restrict__ counts,
                              const float2* __restrict__ meta,
                              const float* __restrict__ gmax,
                              const float* __restrict__ gsum,
                              float4* __restrict__ out4) {
    const int g    = threadIdx.x & 31;
    const int node = (blockIdx.x * blockDim.x + threadIdx.x) >> 5;
    if (node >= kNodes) return;

    const float m = *gmax;
    const float invs = 1.0f / *gsum;

    float4 acc = emb4[(long long)node * 32 + g];  // residual
    const int off = offsets[node];
    const int end = off + counts[node];

    int k = off;
    for (; k + 1 < end; k += 2) {
        const float2 m0 = meta[k];
        const float2 m1 = meta[k + 1];
        const float4 b0 = emb4[(long long)__float_as_int(m0.x) * 32 + g];
        const float4 b1 = emb4[(long long)__float_as_int(m1.x) * 32 + g];
        const float w0 = expf(m0.y - m) * invs;
        const float w1 = expf(m1.y - m) * invs;
        acc.x += w0 * b0.x; acc.y += w0 * b0.y; acc.z += w0 * b0.z; acc.w += w0 * b0.w;
        acc.x += w1 * b1.x; acc.y += w1 * b1.y; acc.z += w1 * b1.z; acc.w += w1 * b1.w;
    }
    if (k < end) {
        const float2 m0 = meta[k];
        const float4 b0 = emb4[(long long)__float_as_int(m0.x) * 32 + g];
        const float w0 = expf(m0.y - m) * invs;
        acc.x += w0 * b0.x; acc.y += w0 * b0.y; acc.z += w0 * b0.z; acc.w += w0 * b0.w;
    }
    out4[(long long)node * 32 + g] = acc;
}

extern "C" void kernel_launch(void* const* d_in, const int* in_sizes, int n_in,
                              void* d_out, int out_size, void* d_ws, size_t ws_size,
                              hipStream_t stream) {
    const float4* emb4 = (const float4*)d_in[0];
    const int2*   rel2 = (const int2*)d_in[1];
    float4* out4 = (float4*)d_out;
    float* wsf = (float*)d_ws;
    int*   wsi = (int*)d_ws;

    float*  gmax     = wsf;
    float*  gsum     = wsf + 1;
    int*    counts   = wsi + kOffCounts;
    int*    offsets  = wsi + kOffOffsets;
    int*    cursor   = wsi + kOffCursor;
    int2*   csrSD    = (int2*)(wsi + kOffCsrSD);
    float2* meta     = (float2*)(wsf + kOffMeta);
    int*    blocksum = wsi + kOffBlockSum;

    hipLaunchKernelGGL(init_kernel, dim3(196), dim3(256), 0, stream, wsf, counts);
    hipLaunchKernelGGL(hist_kernel, dim3(1024), dim3(256), 0, stream, rel2, counts);
    hipLaunchKernelGGL(scanA_kernel, dim3(kScanBlocks), dim3(256), 0, stream, counts, blocksum);
    hipLaunchKernelGGL(scanB_kernel, dim3(1), dim3(64), 0, stream, blocksum);
    hipLaunchKernelGGL(scanC_kernel, dim3(kScanBlocks), dim3(256), 0, stream,
                       counts, blocksum, offsets, cursor);
    hipLaunchKernelGGL(fillsd_kernel, dim3(1024), dim3(256), 0, stream, rel2, cursor, csrSD);
    hipLaunchKernelGGL(scores_csr_kernel, dim3(2048), dim3(256), 0, stream,
                       emb4, csrSD, meta, gmax);
    hipLaunchKernelGGL(sumexp_kernel, dim3(1024), dim3(256), 0, stream, meta, gmax, gsum);
    hipLaunchKernelGGL(gather_kernel, dim3((kNodes + 7) / 8), dim3(256), 0, stream,
                       emb4, offsets, counts, meta, gmax, gsum, out4);
}

// Round 5
// 236.296 us; speedup vs baseline: 1.1438x; 1.1438x over previous
//
#include <hip/hip_runtime.h>
#include <math.h>

constexpr int kNodes = 50000;
constexpr int kDim   = 128;
constexpr int kEdges = 600000;
constexpr float kAlpha = 0.2f;

constexpr int kScanChunk  = 1024;
constexpr int kScanBlocks = (kNodes + kScanChunk - 1) / kScanChunk; // 49

constexpr int kNodesPerBlock = 8;  // 256 threads / 32 lanes-per-node
constexpr int kNodeBlocks = (kNodes + kNodesPerBlock - 1) / kNodesPerBlock;  // 6250

// ws layout (4-byte units):
// [0]=gmax [1]=gsumInv [2..4) pad
constexpr int kOffCounts   = 4;
constexpr int kOffOffsets  = kOffCounts + kNodes;
constexpr int kOffCursor   = kOffOffsets + kNodes;
constexpr int kOffCsrD     = kOffCursor + kNodes;          // int per CSR slot (dst)
constexpr int kOffMeta     = kOffCsrD + kEdges;            // float2 per CSR slot (dst,score); start 754004? -> compute: 4+150000+600000=750004 even ✓
constexpr int kOffPartials = kOffMeta + 2 * kEdges;        // float2 per node-block; 750004+1200000=1950004 even ✓
constexpr int kOffBlockSum = kOffPartials + 2 * kNodeBlocks;

__global__ void init_kernel(int* counts) {
    for (int i = blockIdx.x * blockDim.x + threadIdx.x; i < kNodes; i += gridDim.x * blockDim.x)
        counts[i] = 0;
}

__global__ void hist_kernel(const int2* __restrict__ rel2, int* __restrict__ counts) {
    for (int e = blockIdx.x * blockDim.x + threadIdx.x; e < kEdges; e += gridDim.x * blockDim.x)
        atomicAdd(&counts[rel2[e].x], 1);
}

__global__ void scanA_kernel(const int* __restrict__ counts, int* __restrict__ blocksum) {
    const int base = blockIdx.x * kScanChunk;
    int acc = 0;
    #pragma unroll
    for (int j = 0; j < 4; ++j) {
        const int i = base + 4 * (int)threadIdx.x + j;
        if (i < kNodes) acc += counts[i];
    }
    __shared__ int red[256];
    red[threadIdx.x] = acc;
    __syncthreads();
    for (int s = blockDim.x >> 1; s > 0; s >>= 1) {
        if ((int)threadIdx.x < s) red[threadIdx.x] += red[threadIdx.x + s];
        __syncthreads();
    }
    if (threadIdx.x == 0) blocksum[blockIdx.x] = red[0];
}

// scanC with scanB inlined: every block redundantly scans the 49 chunk sums.
__global__ void scanC_kernel(const int* __restrict__ counts,
                             const int* __restrict__ blocksum,
                             int* __restrict__ offsets,
                             int* __restrict__ cursor) {
    __shared__ int boff[kScanBlocks];
    if ((int)threadIdx.x < kScanBlocks) boff[threadIdx.x] = blocksum[threadIdx.x];
    __syncthreads();
    if (threadIdx.x == 0) {
        int run = 0;
        for (int i = 0; i < kScanBlocks; ++i) { int t = boff[i]; boff[i] = run; run += t; }
    }
    __syncthreads();

    const int base = blockIdx.x * kScanChunk;
    const int lane = threadIdx.x & 63;
    const int wave = threadIdx.x >> 6;
    int c[4];
    int sum4 = 0;
    #pragma unroll
    for (int j = 0; j < 4; ++j) {
        const int i = base + 4 * (int)threadIdx.x + j;
        c[j] = (i < kNodes) ? counts[i] : 0;
        sum4 += c[j];
    }
    int incl = sum4;
    #pragma unroll
    for (int off = 1; off < 64; off <<= 1) {
        int v = __shfl_up(incl, off);
        if (lane >= off) incl += v;
    }
    __shared__ int waveSum[4];
    __shared__ int waveOff[4];
    if (lane == 63) waveSum[wave] = incl;
    __syncthreads();
    if (threadIdx.x == 0) {
        int run = 0;
        for (int w = 0; w < 4; ++w) { int t = waveSum[w]; waveOff[w] = run; run += t; }
    }
    __syncthreads();
    int excl = boff[blockIdx.x] + waveOff[wave] + (incl - sum4);
    #pragma unroll
    for (int j = 0; j < 4; ++j) {
        const int i = base + 4 * (int)threadIdx.x + j;
        if (i < kNodes) { offsets[i] = excl; cursor[i] = excl; }
        excl += c[j];
    }
}

// Scatter dst-only (4 B) into CSR order.
__global__ void fillsd_kernel(const int2* __restrict__ rel2,
                              int* __restrict__ cursor,
                              int* __restrict__ csrD) {
    for (int e = blockIdx.x * blockDim.x + threadIdx.x; e < kEdges; e += gridDim.x * blockDim.x) {
        const int2 sd = rel2[e];
        const int pos = atomicAdd(&cursor[sd.x], 1);
        csrD[pos] = sd.y;
    }
}

__device__ __forceinline__ void onlineMerge(float& m, float& s, float m2, float s2) {
    const float M = fmaxf(m, m2);
    if (M == -INFINITY) { m = M; s = 0.0f; return; }
    s = s * expf(m - M) + s2 * expf(m2 - M);
    m = M;
}

// 32 lanes per node: src row in registers; loop dst rows (unroll x4); dot via
// xor-shuffle; online (m,s) per group -> per-block partial.
__global__ void scoresA_kernel(const float4* __restrict__ emb4,
                               const int* __restrict__ offsets,
                               const int* __restrict__ counts,
                               const int* __restrict__ csrD,
                               float2* __restrict__ meta,
                               float2* __restrict__ partials) {
    const int g   = threadIdx.x & 31;
    const int grp = threadIdx.x >> 5;
    const int node = blockIdx.x * kNodesPerBlock + grp;

    float m_run = -INFINITY, s_run = 0.0f;

    if (node < kNodes) {
        const float4 a = emb4[(long long)node * 32 + g];
        const int off = offsets[node];
        const int end = off + counts[node];
        int k = off;
        for (; k + 3 < end; k += 4) {
            const int d0 = csrD[k], d1 = csrD[k+1], d2 = csrD[k+2], d3 = csrD[k+3];
            const float4 b0 = emb4[(long long)d0 * 32 + g];
            const float4 b1 = emb4[(long long)d1 * 32 + g];
            const float4 b2 = emb4[(long long)d2 * 32 + g];
            const float4 b3 = emb4[(long long)d3 * 32 + g];
            float p0 = a.x*b0.x + a.y*b0.y + a.z*b0.z + a.w*b0.w;
            float p1 = a.x*b1.x + a.y*b1.y + a.z*b1.z + a.w*b1.w;
            float p2 = a.x*b2.x + a.y*b2.y + a.z*b2.z + a.w*b2.w;
            float p3 = a.x*b3.x + a.y*b3.y + a.z*b3.z + a.w*b3.w;
            #pragma unroll
            for (int o = 16; o > 0; o >>= 1) {
                p0 += __shfl_xor(p0, o); p1 += __shfl_xor(p1, o);
                p2 += __shfl_xor(p2, o); p3 += __shfl_xor(p3, o);
            }
            const float s0 = p0 > 0.f ? p0 : kAlpha * p0;
            const float s1 = p1 > 0.f ? p1 : kAlpha * p1;
            const float s2 = p2 > 0.f ? p2 : kAlpha * p2;
            const float s3 = p3 > 0.f ? p3 : kAlpha * p3;
            // merge 4 scores into running (m,s)
            const float m4 = fmaxf(fmaxf(s0, s1), fmaxf(s2, s3));
            const float e4 = expf(s0 - m4) + expf(s1 - m4) + expf(s2 - m4) + expf(s3 - m4);
            onlineMerge(m_run, s_run, m4, e4);
            if (g == 0) {
                meta[k]   = make_float2(__int_as_float(d0), s0);
                meta[k+1] = make_float2(__int_as_float(d1), s1);
                meta[k+2] = make_float2(__int_as_float(d2), s2);
                meta[k+3] = make_float2(__int_as_float(d3), s3);
            }
        }
        for (; k < end; ++k) {
            const int d0 = csrD[k];
            const float4 b0 = emb4[(long long)d0 * 32 + g];
            float p0 = a.x*b0.x + a.y*b0.y + a.z*b0.z + a.w*b0.w;
            #pragma unroll
            for (int o = 16; o > 0; o >>= 1) p0 += __shfl_xor(p0, o);
            const float s0 = p0 > 0.f ? p0 : kAlpha * p0;
            onlineMerge(m_run, s_run, s0, 1.0f);
            if (g == 0) meta[k] = make_float2(__int_as_float(d0), s0);
        }
    }

    __shared__ float sm[kNodesPerBlock];
    __shared__ float ss[kNodesPerBlock];
    if (g == 0) { sm[grp] = m_run; ss[grp] = s_run; }
    __syncthreads();
    if (threadIdx.x == 0) {
        float M = sm[0], S = ss[0];
        #pragma unroll
        for (int i = 1; i < kNodesPerBlock; ++i) onlineMerge(M, S, sm[i], ss[i]);
        partials[blockIdx.x] = make_float2(M, S);
    }
}

// Single block: reduce 6250 block partials -> gmax, 1/gsum.
__global__ void finalize_kernel(const float2* __restrict__ partials, float* __restrict__ wsf) {
    float M = -INFINITY, S = 0.0f;
    for (int i = threadIdx.x; i < kNodeBlocks; i += blockDim.x) {
        const float2 p = partials[i];
        onlineMerge(M, S, p.x, p.y);
    }
    __shared__ float sm[1024];
    __shared__ float ss[1024];
    sm[threadIdx.x] = M; ss[threadIdx.x] = S;
    __syncthreads();
    for (int s = blockDim.x >> 1; s > 0; s >>= 1) {
        if ((int)threadIdx.x < s) {
            float m1 = sm[threadIdx.x], s1 = ss[threadIdx.x];
            onlineMerge(m1, s1, sm[threadIdx.x + s], ss[threadIdx.x + s]);
            sm[threadIdx.x] = m1; ss[threadIdx.x] = s1;
        }
        __syncthreads();
    }
    if (threadIdx.x == 0) { wsf[0] = sm[0]; wsf[1] = 1.0f / ss[0]; }
}

// 32 lanes per node; unroll x4.
__global__ void gather_kernel(const float4* __restrict__ emb4,
                              const int* __restrict__ offsets,
                              const int* __restrict__ counts,
                              const float2* __restrict__ meta,
                              const float* __restrict__ wsf,
                              float4* __restrict__ out4) {
    const int g    = threadIdx.x & 31;
    const int node = (blockIdx.x * blockDim.x + threadIdx.x) >> 5;
    if (node >= kNodes) return;

    const float m    = wsf[0];
    const float invs = wsf[1];

    float4 acc = emb4[(long long)node * 32 + g];  // residual
    const int off = offsets[node];
    const int end = off + counts[node];

    int k = off;
    for (; k + 3 < end; k += 4) {
        const float2 m0 = meta[k];
        const float2 m1 = meta[k + 1];
        const float2 m2 = meta[k + 2];
        const float2 m3 = meta[k + 3];
        const float4 b0 = emb4[(long long)__float_as_int(m0.x) * 32 + g];
        const float4 b1 = emb4[(long long)__float_as_int(m1.x) * 32 + g];
        const float4 b2 = emb4[(long long)__float_as_int(m2.x) * 32 + g];
        const float4 b3 = emb4[(long long)__float_as_int(m3.x) * 32 + g];
        const float w0 = expf(m0.y - m) * invs;
        const float w1 = expf(m1.y - m) * invs;
        const float w2 = expf(m2.y - m) * invs;
        const float w3 = expf(m3.y - m) * invs;
        acc.x += w0 * b0.x; acc.y += w0 * b0.y; acc.z += w0 * b0.z; acc.w += w0 * b0.w;
        acc.x += w1 * b1.x; acc.y += w1 * b1.y; acc.z += w1 * b1.z; acc.w += w1 * b1.w;
        acc.x += w2 * b2.x; acc.y += w2 * b2.y; acc.z += w2 * b2.z; acc.w += w2 * b2.w;
        acc.x += w3 * b3.x; acc.y += w3 * b3.y; acc.z += w3 * b3.z; acc.w += w3 * b3.w;
    }
    for (; k < end; ++k) {
        const float2 m0 = meta[k];
        const float4 b0 = emb4[(long long)__float_as_int(m0.x) * 32 + g];
        const float w0 = expf(m0.y - m) * invs;
        acc.x += w0 * b0.x; acc.y += w0 * b0.y; acc.z += w0 * b0.z; acc.w += w0 * b0.w;
    }
    out4[(long long)node * 32 + g] = acc;
}

extern "C" void kernel_launch(void* const* d_in, const int* in_sizes, int n_in,
                              void* d_out, int out_size, void* d_ws, size_t ws_size,
                              hipStream_t stream) {
    const float4* emb4 = (const float4*)d_in[0];
    const int2*   rel2 = (const int2*)d_in[1];
    float4* out4 = (float4*)d_out;
    float* wsf = (float*)d_ws;
    int*   wsi = (int*)d_ws;

    int*    counts   = wsi + kOffCounts;
    int*    offsets  = wsi + kOffOffsets;
    int*    cursor   = wsi + kOffCursor;
    int*    csrD     = wsi + kOffCsrD;
    float2* meta     = (float2*)(wsf + kOffMeta);
    float2* partials = (float2*)(wsf + kOffPartials);
    int*    blocksum = wsi + kOffBlockSum;

    hipLaunchKernelGGL(init_kernel, dim3(128), dim3(256), 0, stream, counts);
    hipLaunchKernelGGL(hist_kernel, dim3(1024), dim3(256), 0, stream, rel2, counts);
    hipLaunchKernelGGL(scanA_kernel, dim3(kScanBlocks), dim3(256), 0, stream, counts, blocksum);
    hipLaunchKernelGGL(scanC_kernel, dim3(kScanBlocks), dim3(256), 0, stream,
                       counts, blocksum, offsets, cursor);
    hipLaunchKernelGGL(fillsd_kernel, dim3(1024), dim3(256), 0, stream, rel2, cursor, csrD);
    hipLaunchKernelGGL(scoresA_kernel, dim3(kNodeBlocks), dim3(256), 0, stream,
                       emb4, offsets, counts, csrD, meta, partials);
    hipLaunchKernelGGL(finalize_kernel, dim3(1), dim3(1024), 0, stream, partials, wsf);
    hipLaunchKernelGGL(gather_kernel, dim3(kNodeBlocks), dim3(256), 0, stream,
                       emb4, offsets, counts, meta, wsf, out4);
}

// Round 6
// 202.812 us; speedup vs baseline: 1.3327x; 1.1651x over previous
//
#include <hip/hip_runtime.h>
#include <math.h>

constexpr int kNodes = 50000;
constexpr int kEdges = 600000;
constexpr float kAlpha = 0.2f;
constexpr float kNegBig = -1e30f;

constexpr int kScanChunk  = 1024;
constexpr int kScanBlocks = (kNodes + kScanChunk - 1) / kScanChunk; // 49

constexpr int kNodesPerBlock = 8;   // 256 threads / 32 lanes-per-node
constexpr int kNodeBlocks = kNodes / kNodesPerBlock;  // 6250 exactly

// ws layout (4-byte units): [0]=gmax [1]=gsumInv [2..4) pad
constexpr int kOffCounts   = 4;
constexpr int kOffOffsets  = kOffCounts + kNodes;
constexpr int kOffCursor   = kOffOffsets + kNodes;
constexpr int kOffCsrD     = kOffCursor + kNodes;        // int per CSR slot (dst)
constexpr int kOffMnode    = kOffCsrD + kEdges;          // float per node (running max)
constexpr int kOffPartials = kOffMnode + kNodes;         // float2 per node-block (even offset: 800004 ✓)
constexpr int kOffBlockSum = kOffPartials + 2 * kNodeBlocks;

__global__ void hist_kernel(const int2* __restrict__ rel2, int* __restrict__ counts) {
    for (int e = blockIdx.x * blockDim.x + threadIdx.x; e < kEdges; e += gridDim.x * blockDim.x)
        atomicAdd(&counts[rel2[e].x], 1);
}

__global__ void scanA_kernel(const int* __restrict__ counts, int* __restrict__ blocksum) {
    const int base = blockIdx.x * kScanChunk;
    int acc = 0;
    #pragma unroll
    for (int j = 0; j < 4; ++j) {
        const int i = base + 4 * (int)threadIdx.x + j;
        if (i < kNodes) acc += counts[i];
    }
    __shared__ int red[256];
    red[threadIdx.x] = acc;
    __syncthreads();
    for (int s = blockDim.x >> 1; s > 0; s >>= 1) {
        if ((int)threadIdx.x < s) red[threadIdx.x] += red[threadIdx.x + s];
        __syncthreads();
    }
    if (threadIdx.x == 0) blocksum[blockIdx.x] = red[0];
}

// scanC with scanB inlined.
__global__ void scanC_kernel(const int* __restrict__ counts,
                             const int* __restrict__ blocksum,
                             int* __restrict__ offsets,
                             int* __restrict__ cursor) {
    __shared__ int boff[kScanBlocks];
    if ((int)threadIdx.x < kScanBlocks) boff[threadIdx.x] = blocksum[threadIdx.x];
    __syncthreads();
    if (threadIdx.x == 0) {
        int run = 0;
        for (int i = 0; i < kScanBlocks; ++i) { int t = boff[i]; boff[i] = run; run += t; }
    }
    __syncthreads();

    const int base = blockIdx.x * kScanChunk;
    const int lane = threadIdx.x & 63;
    const int wave = threadIdx.x >> 6;
    int c[4];
    int sum4 = 0;
    #pragma unroll
    for (int j = 0; j < 4; ++j) {
        const int i = base + 4 * (int)threadIdx.x + j;
        c[j] = (i < kNodes) ? counts[i] : 0;
        sum4 += c[j];
    }
    int incl = sum4;
    #pragma unroll
    for (int off = 1; off < 64; off <<= 1) {
        int v = __shfl_up(incl, off);
        if (lane >= off) incl += v;
    }
    __shared__ int waveSum[4];
    __shared__ int waveOff[4];
    if (lane == 63) waveSum[wave] = incl;
    __syncthreads();
    if (threadIdx.x == 0) {
        int run = 0;
        for (int w = 0; w < 4; ++w) { int t = waveSum[w]; waveOff[w] = run; run += t; }
    }
    __syncthreads();
    int excl = boff[blockIdx.x] + waveOff[wave] + (incl - sum4);
    #pragma unroll
    for (int j = 0; j < 4; ++j) {
        const int i = base + 4 * (int)threadIdx.x + j;
        if (i < kNodes) { offsets[i] = excl; cursor[i] = excl; }
        excl += c[j];
    }
}

__global__ void fillsd_kernel(const int2* __restrict__ rel2,
                              int* __restrict__ cursor,
                              int* __restrict__ csrD) {
    for (int e = blockIdx.x * blockDim.x + threadIdx.x; e < kEdges; e += gridDim.x * blockDim.x) {
        const int2 sd = rel2[e];
        const int pos = atomicAdd(&cursor[sd.x], 1);
        csrD[pos] = sd.y;
    }
}

__device__ __forceinline__ void onlineMerge(float& m, float& s, float m2, float s2) {
    const float M = fmaxf(m, m2);
    s = s * expf(m - M) + s2 * expf(m2 - M);
    m = M;
}

// Fused: 32 lanes per node. src row in registers; per dst row (loaded once):
// dot -> score -> online-softmax accumulate UNNORMALIZED output into d_out.
__global__ void scores_fused_kernel(const float4* __restrict__ emb4,
                                    const int* __restrict__ offsets,
                                    const int* __restrict__ counts,
                                    const int* __restrict__ csrD,
                                    float* __restrict__ mnode,
                                    float2* __restrict__ partials,
                                    float4* __restrict__ out4) {
    const int g   = threadIdx.x & 31;
    const int grp = threadIdx.x >> 5;
    const int node = blockIdx.x * kNodesPerBlock + grp;  // always < kNodes (50000 = 6250*8)

    const float4 a = emb4[(long long)node * 32 + g];
    float4 acc = make_float4(0.f, 0.f, 0.f, 0.f);
    float m_run = kNegBig, s_run = 0.0f;

    const int off = offsets[node];
    const int end = off + counts[node];
    int k = off;
    for (; k + 3 < end; k += 4) {
        const int d0 = csrD[k], d1 = csrD[k+1], d2 = csrD[k+2], d3 = csrD[k+3];
        const float4 b0 = emb4[(long long)d0 * 32 + g];
        const float4 b1 = emb4[(long long)d1 * 32 + g];
        const float4 b2 = emb4[(long long)d2 * 32 + g];
        const float4 b3 = emb4[(long long)d3 * 32 + g];
        float p0 = a.x*b0.x + a.y*b0.y + a.z*b0.z + a.w*b0.w;
        float p1 = a.x*b1.x + a.y*b1.y + a.z*b1.z + a.w*b1.w;
        float p2 = a.x*b2.x + a.y*b2.y + a.z*b2.z + a.w*b2.w;
        float p3 = a.x*b3.x + a.y*b3.y + a.z*b3.z + a.w*b3.w;
        #pragma unroll
        for (int o = 16; o > 0; o >>= 1) {
            p0 += __shfl_xor(p0, o); p1 += __shfl_xor(p1, o);
            p2 += __shfl_xor(p2, o); p3 += __shfl_xor(p3, o);
        }
        const float s0 = p0 > 0.f ? p0 : kAlpha * p0;
        const float s1 = p1 > 0.f ? p1 : kAlpha * p1;
        const float s2 = p2 > 0.f ? p2 : kAlpha * p2;
        const float s3 = p3 > 0.f ? p3 : kAlpha * p3;
        const float m4 = fmaxf(fmaxf(s0, s1), fmaxf(s2, s3));
        const float newM = fmaxf(m_run, m4);
        const float rs = expf(m_run - newM);       // underflows to 0 when m_run = -1e30
        const float w0 = expf(s0 - newM);
        const float w1 = expf(s1 - newM);
        const float w2 = expf(s2 - newM);
        const float w3 = expf(s3 - newM);
        s_run = s_run * rs + (w0 + w1 + w2 + w3);
        acc.x = acc.x * rs + w0*b0.x + w1*b1.x + w2*b2.x + w3*b3.x;
        acc.y = acc.y * rs + w0*b0.y + w1*b1.y + w2*b2.y + w3*b3.y;
        acc.z = acc.z * rs + w0*b0.z + w1*b1.z + w2*b2.z + w3*b3.z;
        acc.w = acc.w * rs + w0*b0.w + w1*b1.w + w2*b2.w + w3*b3.w;
        m_run = newM;
    }
    for (; k < end; ++k) {
        const int d0 = csrD[k];
        const float4 b0 = emb4[(long long)d0 * 32 + g];
        float p0 = a.x*b0.x + a.y*b0.y + a.z*b0.z + a.w*b0.w;
        #pragma unroll
        for (int o = 16; o > 0; o >>= 1) p0 += __shfl_xor(p0, o);
        const float s0 = p0 > 0.f ? p0 : kAlpha * p0;
        const float newM = fmaxf(m_run, s0);
        const float rs = expf(m_run - newM);
        const float w0 = expf(s0 - newM);
        s_run = s_run * rs + w0;
        acc.x = acc.x * rs + w0*b0.x;
        acc.y = acc.y * rs + w0*b0.y;
        acc.z = acc.z * rs + w0*b0.z;
        acc.w = acc.w * rs + w0*b0.w;
        m_run = newM;
    }
    out4[(long long)node * 32 + g] = acc;   // unnormalized
    if (g == 0) mnode[node] = m_run;

    __shared__ float sm[kNodesPerBlock];
    __shared__ float ss[kNodesPerBlock];
    if (g == 0) { sm[grp] = m_run; ss[grp] = s_run; }
    __syncthreads();
    if (threadIdx.x == 0) {
        float M = sm[0], S = ss[0];
        #pragma unroll
        for (int i = 1; i < kNodesPerBlock; ++i) onlineMerge(M, S, sm[i], ss[i]);
        partials[blockIdx.x] = make_float2(M, S);
    }
}

__global__ void finalize_kernel(const float2* __restrict__ partials, float* __restrict__ wsf) {
    float M = kNegBig, S = 0.0f;
    for (int i = threadIdx.x; i < kNodeBlocks; i += blockDim.x) {
        const float2 p = partials[i];
        onlineMerge(M, S, p.x, p.y);
    }
    __shared__ float sm[1024];
    __shared__ float ss[1024];
    sm[threadIdx.x] = M; ss[threadIdx.x] = S;
    __syncthreads();
    for (int s = blockDim.x >> 1; s > 0; s >>= 1) {
        if ((int)threadIdx.x < s) {
            float m1 = sm[threadIdx.x], s1 = ss[threadIdx.x];
            onlineMerge(m1, s1, sm[threadIdx.x + s], ss[threadIdx.x + s]);
            sm[threadIdx.x] = m1; ss[threadIdx.x] = s1;
        }
        __syncthreads();
    }
    if (threadIdx.x == 0) { wsf[0] = sm[0]; wsf[1] = 1.0f / ss[0]; }
}

// out = emb + out * exp(m_node - M) / S  (elementwise, float4 per thread)
__global__ void epilogue_kernel(const float4* __restrict__ emb4,
                                const float* __restrict__ mnode,
                                const float* __restrict__ wsf,
                                float4* __restrict__ out4) {
    const int i = blockIdx.x * blockDim.x + threadIdx.x;
    if (i >= kNodes * 32) return;
    const int node = i >> 5;
    const float scale = expf(mnode[node] - wsf[0]) * wsf[1];
    const float4 o = out4[i];
    const float4 e = emb4[i];
    out4[i] = make_float4(e.x + scale * o.x, e.y + scale * o.y,
                          e.z + scale * o.z, e.w + scale * o.w);
}

extern "C" void kernel_launch(void* const* d_in, const int* in_sizes, int n_in,
                              void* d_out, int out_size, void* d_ws, size_t ws_size,
                              hipStream_t stream) {
    const float4* emb4 = (const float4*)d_in[0];
    const int2*   rel2 = (const int2*)d_in[1];
    float4* out4 = (float4*)d_out;
    float* wsf = (float*)d_ws;
    int*   wsi = (int*)d_ws;

    int*    counts   = wsi + kOffCounts;
    int*    offsets  = wsi + kOffOffsets;
    int*    cursor   = wsi + kOffCursor;
    int*    csrD     = wsi + kOffCsrD;
    float*  mnode    = wsf + kOffMnode;
    float2* partials = (float2*)(wsf + kOffPartials);
    int*    blocksum = wsi + kOffBlockSum;

    hipMemsetAsync(counts, 0, kNodes * sizeof(int), stream);
    hipLaunchKernelGGL(hist_kernel, dim3(1024), dim3(256), 0, stream, rel2, counts);
    hipLaunchKernelGGL(scanA_kernel, dim3(kScanBlocks), dim3(256), 0, stream, counts, blocksum);
    hipLaunchKernelGGL(scanC_kernel, dim3(kScanBlocks), dim3(256), 0, stream,
                       counts, blocksum, offsets, cursor);
    hipLaunchKernelGGL(fillsd_kernel, dim3(1024), dim3(256), 0, stream, rel2, cursor, csrD);
    hipLaunchKernelGGL(scores_fused_kernel, dim3(kNodeBlocks), dim3(256), 0, stream,
                       emb4, offsets, counts, csrD, mnode, partials, out4);
    hipLaunchKernelGGL(finalize_kernel, dim3(1), dim3(1024), 0, stream, partials, wsf);
    hipLaunchKernelGGL(epilogue_kernel, dim3((kNodes * 32 + 255) / 256), dim3(256), 0, stream,
                       emb4, mnode, wsf, out4);
}